// Round 1
// baseline (718.520 us; speedup 1.0000x reference)
//
#include <hip/hip_runtime.h>
#include <hip/hip_bf16.h>
#include <math.h>

// Problem constants (fixed by the reference)
#define NT    10000      // total nodes (BL*N)
#define NE    120000     // edges
#define HEADS 4
#define HIDC  128        // per-head channels, layers 0/1
#define OUTC  256        // layer 2 channels (1 head)

// ---------------------------------------------------------------------------
// CSR build: histogram by dst -> exclusive scan -> scatter (src, weight)
// ---------------------------------------------------------------------------
__global__ void hist_kernel(const int* __restrict__ dst, int* __restrict__ cnt, int E) {
    int e = blockIdx.x * 256 + threadIdx.x;
    if (e < E) atomicAdd(&cnt[dst[e]], 1);
}

__global__ __launch_bounds__(1024) void scan_kernel(const int* __restrict__ cnt,
                                                    int* __restrict__ rowptr, int n) {
    __shared__ int part[1024];
    int tid = threadIdx.x;
    const int PER = (n + 1023) / 1024 + 1;   // generous cover of n+1 entries
    int base = tid * PER;
    int s = 0;
    for (int i = 0; i < PER; ++i) {
        int idx = base + i;
        if (idx < n) s += cnt[idx];
    }
    part[tid] = s;
    __syncthreads();
    for (int off = 1; off < 1024; off <<= 1) {
        int v = (tid >= off) ? part[tid - off] : 0;
        __syncthreads();
        part[tid] += v;
        __syncthreads();
    }
    int run = (tid == 0) ? 0 : part[tid - 1];
    for (int i = 0; i < PER; ++i) {
        int idx = base + i;
        if (idx < n) { rowptr[idx] = run; run += cnt[idx]; }
        else if (idx == n) rowptr[idx] = run;
    }
}

__global__ void scatter_kernel(const int* __restrict__ src, const int* __restrict__ dst,
                               const float* __restrict__ ew,
                               const int* __restrict__ rowptr, int* __restrict__ cursor,
                               int* __restrict__ csr_src, float* __restrict__ csr_w, int E) {
    int e = blockIdx.x * 256 + threadIdx.x;
    if (e >= E) return;
    int d = dst[e];
    int pos = atomicAdd(&cursor[d], 1);
    int idx = rowptr[d] + pos;
    csr_src[idx] = src[e];
    csr_w[idx]  = ew[e];
}

// ---------------------------------------------------------------------------
// fp32 GEMM with bias: C[M,N] = A[M,K] @ W[K,N] + bias[N]
// 64x64 tile, BK=16, 256 threads, 4x4 per thread.
// ---------------------------------------------------------------------------
#define TBM 64
#define TBN 64
#define TBK 16

__global__ __launch_bounds__(256) void gemm_bias_kernel(
    const float* __restrict__ A, const float* __restrict__ W,
    const float* __restrict__ bias, float* __restrict__ Cout,
    int M, int N, int K)
{
    __shared__ float As[TBM][TBK + 1];   // +1 pad: conflict-free column reads
    __shared__ float Bs[TBK][TBN + 4];   // +4 pad keeps 16B alignment

    int tid = threadIdx.x;
    int bm = blockIdx.x * TBM;
    int bn = blockIdx.y * TBN;
    int tx = tid & 15, ty = tid >> 4;

    int arow = tid >> 2, ak = (tid & 3) * 4;   // A: one float4 per thread
    int brow = tid >> 4, bc = (tid & 15) * 4;  // B: one float4 per thread

    float acc[4][4] = {};

    for (int k0 = 0; k0 < K; k0 += TBK) {
        float4 av = make_float4(0.f, 0.f, 0.f, 0.f);
        if (bm + arow < M)
            av = *reinterpret_cast<const float4*>(A + (size_t)(bm + arow) * K + k0 + ak);
        As[arow][ak + 0] = av.x;
        As[arow][ak + 1] = av.y;
        As[arow][ak + 2] = av.z;
        As[arow][ak + 3] = av.w;
        float4 bv = *reinterpret_cast<const float4*>(W + (size_t)(k0 + brow) * N + bn + bc);
        *reinterpret_cast<float4*>(&Bs[brow][bc]) = bv;
        __syncthreads();

        #pragma unroll
        for (int kk = 0; kk < TBK; ++kk) {
            float a0 = As[ty * 4 + 0][kk];
            float a1 = As[ty * 4 + 1][kk];
            float a2 = As[ty * 4 + 2][kk];
            float a3 = As[ty * 4 + 3][kk];
            float4 b = *reinterpret_cast<const float4*>(&Bs[kk][tx * 4]);
            acc[0][0] += a0 * b.x; acc[0][1] += a0 * b.y; acc[0][2] += a0 * b.z; acc[0][3] += a0 * b.w;
            acc[1][0] += a1 * b.x; acc[1][1] += a1 * b.y; acc[1][2] += a1 * b.z; acc[1][3] += a1 * b.w;
            acc[2][0] += a2 * b.x; acc[2][1] += a2 * b.y; acc[2][2] += a2 * b.z; acc[2][3] += a2 * b.w;
            acc[3][0] += a3 * b.x; acc[3][1] += a3 * b.y; acc[3][2] += a3 * b.z; acc[3][3] += a3 * b.w;
        }
        __syncthreads();
    }

    float4 bb = *reinterpret_cast<const float4*>(bias + bn + tx * 4);
    #pragma unroll
    for (int i = 0; i < 4; ++i) {
        int row = bm + ty * 4 + i;
        if (row < M) {
            float4 o;
            o.x = acc[i][0] + bb.x;
            o.y = acc[i][1] + bb.y;
            o.z = acc[i][2] + bb.z;
            o.w = acc[i][3] + bb.w;
            *reinterpret_cast<float4*>(Cout + (size_t)row * N + bn + tx * 4) = o;
        }
    }
}

// ---------------------------------------------------------------------------
// Edge attention + segment softmax + aggregation. One wave per (node, head).
// Pass 1: logits per incoming edge (stored in scratch), running max.
// Pass 2: p = exp(l-m); accumulate p and p*xl[src]; out = acc/(s+eps)+bias [elu]
// ---------------------------------------------------------------------------
template<int C, int H, bool DO_ELU>
__global__ __launch_bounds__(256) void edge_attn_kernel(
    const float* __restrict__ xl, const float* __restrict__ xr,
    const int* __restrict__ rowptr, const int* __restrict__ csr_src,
    const float* __restrict__ csr_w,
    const float* __restrict__ We, const float* __restrict__ att,
    const float* __restrict__ bias,
    float* __restrict__ logits_ws, float* __restrict__ out, int nt)
{
    constexpr int VPT = C / 64;
    int gwave = (blockIdx.x * 256 + threadIdx.x) >> 6;
    int lane = threadIdx.x & 63;
    if (gwave >= nt * H) return;
    int node = gwave / H;
    int h = gwave - node * H;
    int c0 = lane * VPT;

    size_t nbase = ((size_t)node * H + h) * C + c0;

    float xr_reg[VPT], we_reg[VPT], att_reg[VPT], bias_reg[VPT];
    #pragma unroll
    for (int v = 0; v < VPT; ++v) {
        xr_reg[v]   = xr[nbase + v];
        we_reg[v]   = We[h * C + c0 + v];
        att_reg[v]  = att[h * C + c0 + v];
        bias_reg[v] = bias[h * C + c0 + v];
    }

    int rs = rowptr[node];
    int re = rowptr[node + 1];

    // Pass 1: logits + max
    float m = -INFINITY;
    for (int i = rs; i < re; ++i) {
        int s = csr_src[i];
        float w = csr_w[i];
        const float* xlp = xl + ((size_t)s * H + h) * C + c0;
        float xlv[VPT];
        if (VPT == 2) {
            float2 t = *reinterpret_cast<const float2*>(xlp);
            xlv[0] = t.x; xlv[1] = t.y;
        } else {
            float4 t = *reinterpret_cast<const float4*>(xlp);
            xlv[0] = t.x; xlv[1] = t.y; xlv[2] = t.z; xlv[3] = t.w;
        }
        float acc = 0.f;
        #pragma unroll
        for (int v = 0; v < VPT; ++v) {
            float t = xlv[v] + xr_reg[v] + w * we_reg[v];
            t = (t > 0.f) ? t : 0.2f * t;
            acc += t * att_reg[v];
        }
        #pragma unroll
        for (int off = 32; off > 0; off >>= 1) acc += __shfl_xor(acc, off, 64);
        if (lane == 0) logits_ws[(size_t)i * H + h] = acc;
        m = fmaxf(m, acc);
    }

    // Pass 2: softmax-weighted aggregation
    float ssum = 0.f;
    float av[VPT];
    #pragma unroll
    for (int v = 0; v < VPT; ++v) av[v] = 0.f;
    for (int i = rs; i < re; ++i) {
        float l = logits_ws[(size_t)i * H + h];
        float p = __expf(l - m);
        ssum += p;
        int s = csr_src[i];
        const float* xlp = xl + ((size_t)s * H + h) * C + c0;
        float xlv[VPT];
        if (VPT == 2) {
            float2 t = *reinterpret_cast<const float2*>(xlp);
            xlv[0] = t.x; xlv[1] = t.y;
        } else {
            float4 t = *reinterpret_cast<const float4*>(xlp);
            xlv[0] = t.x; xlv[1] = t.y; xlv[2] = t.z; xlv[3] = t.w;
        }
        #pragma unroll
        for (int v = 0; v < VPT; ++v) av[v] += p * xlv[v];
    }

    float inv = 1.f / (ssum + 1e-16f);
    #pragma unroll
    for (int v = 0; v < VPT; ++v) {
        float o = av[v] * inv + bias_reg[v];
        if (DO_ELU) o = (o > 0.f) ? o : (__expf(o) - 1.f);
        out[nbase + v] = o;
    }
}

// ---------------------------------------------------------------------------
extern "C" void kernel_launch(void* const* d_in, const int* in_sizes, int n_in,
                              void* d_out, int out_size, void* d_ws, size_t ws_size,
                              hipStream_t stream) {
    const float* x   = (const float*)d_in[0];
    const int*   ei  = (const int*)d_in[1];
    const float* ew  = (const float*)d_in[2];
    const int* srcp = ei;
    const int* dstp = ei + NE;

    // Per-layer weights: Wl, bl, Wr, br, We, att, bias starting at index 3
    const float* Wl[3]; const float* bl[3]; const float* Wr[3]; const float* br[3];
    const float* We[3]; const float* at[3]; const float* bi[3];
    for (int l = 0; l < 3; ++l) {
        int b = 3 + 7 * l;
        Wl[l] = (const float*)d_in[b + 0];
        bl[l] = (const float*)d_in[b + 1];
        Wr[l] = (const float*)d_in[b + 2];
        br[l] = (const float*)d_in[b + 3];
        We[l] = (const float*)d_in[b + 4];
        at[l] = (const float*)d_in[b + 5];
        bi[l] = (const float*)d_in[b + 6];
    }

    // Workspace carve-up (256B aligned)
    size_t off = 0;
    auto alloc = [&](size_t bytes) -> void* {
        void* p = (char*)d_ws + off;
        off += (bytes + 255) & ~(size_t)255;
        return p;
    };
    float* xl      = (float*)alloc((size_t)NT * 512 * 4);
    float* xr      = (float*)alloc((size_t)NT * 512 * 4);
    float* act     = (float*)alloc((size_t)NT * 512 * 4);
    float* logits  = (float*)alloc((size_t)NE * HEADS * 4);
    int*   rowptr  = (int*)alloc((size_t)(NT + 1) * 4);
    int*   cnt     = (int*)alloc((size_t)NT * 4);
    int*   cursor  = (int*)alloc((size_t)NT * 4);
    int*   csr_src = (int*)alloc((size_t)NE * 4);
    float* csr_w   = (float*)alloc((size_t)NE * 4);

    hipMemsetAsync(cnt, 0, (size_t)NT * 4, stream);
    hipMemsetAsync(cursor, 0, (size_t)NT * 4, stream);

    int eblocks = (NE + 255) / 256;
    hist_kernel<<<eblocks, 256, 0, stream>>>(dstp, cnt, NE);
    scan_kernel<<<1, 1024, 0, stream>>>(cnt, rowptr, NT);
    scatter_kernel<<<eblocks, 256, 0, stream>>>(srcp, dstp, ew, rowptr, cursor,
                                                csr_src, csr_w, NE);

    int mblocks = (NT + TBM - 1) / TBM;

    // ---- Layer 0: K=64, N=512, H=4, C=128, ELU
    {
        dim3 g(mblocks, 512 / TBN);
        gemm_bias_kernel<<<g, 256, 0, stream>>>(x, Wl[0], bl[0], xl, NT, 512, 64);
        gemm_bias_kernel<<<g, 256, 0, stream>>>(x, Wr[0], br[0], xr, NT, 512, 64);
        int blocks = (NT * HEADS + 3) / 4;
        edge_attn_kernel<128, 4, true><<<blocks, 256, 0, stream>>>(
            xl, xr, rowptr, csr_src, csr_w, We[0], at[0], bi[0], logits, act, NT);
    }

    // ---- Layer 1: K=512, N=512, H=4, C=128, ELU
    {
        dim3 g(mblocks, 512 / TBN);
        gemm_bias_kernel<<<g, 256, 0, stream>>>(act, Wl[1], bl[1], xl, NT, 512, 512);
        gemm_bias_kernel<<<g, 256, 0, stream>>>(act, Wr[1], br[1], xr, NT, 512, 512);
        int blocks = (NT * HEADS + 3) / 4;
        edge_attn_kernel<128, 4, true><<<blocks, 256, 0, stream>>>(
            xl, xr, rowptr, csr_src, csr_w, We[1], at[1], bi[1], logits, act, NT);
    }

    // ---- Layer 2: K=512, N=256, H=1, C=256, no ELU, write d_out
    {
        dim3 g(mblocks, 256 / TBN);
        gemm_bias_kernel<<<g, 256, 0, stream>>>(act, Wl[2], bl[2], xl, NT, 256, 512);
        gemm_bias_kernel<<<g, 256, 0, stream>>>(act, Wr[2], br[2], xr, NT, 256, 512);
        int blocks = (NT + 3) / 4;
        edge_attn_kernel<256, 1, false><<<blocks, 256, 0, stream>>>(
            xl, xr, rowptr, csr_src, csr_w, We[2], at[2], bi[2], logits, (float*)d_out, NT);
    }
}

// Round 2
// 591.222 us; speedup vs baseline: 1.2153x; 1.2153x over previous
//
#include <hip/hip_runtime.h>
#include <hip/hip_bf16.h>
#include <math.h>

// Problem constants (fixed by the reference)
#define NT    10000      // total nodes (BL*N)
#define NE    120000     // edges
#define HEADS 4

// ---------------------------------------------------------------------------
// CSR build: histogram by dst -> exclusive scan -> scatter (src, weight)
// ---------------------------------------------------------------------------
__global__ void hist_kernel(const int* __restrict__ dst, int* __restrict__ cnt, int E) {
    int e = blockIdx.x * 256 + threadIdx.x;
    if (e < E) atomicAdd(&cnt[dst[e]], 1);
}

__global__ __launch_bounds__(1024) void scan_kernel(const int* __restrict__ cnt,
                                                    int* __restrict__ rowptr, int n) {
    __shared__ int part[1024];
    int tid = threadIdx.x;
    const int PER = (n + 1023) / 1024 + 1;
    int base = tid * PER;
    int s = 0;
    for (int i = 0; i < PER; ++i) {
        int idx = base + i;
        if (idx < n) s += cnt[idx];
    }
    part[tid] = s;
    __syncthreads();
    for (int off = 1; off < 1024; off <<= 1) {
        int v = (tid >= off) ? part[tid - off] : 0;
        __syncthreads();
        part[tid] += v;
        __syncthreads();
    }
    int run = (tid == 0) ? 0 : part[tid - 1];
    for (int i = 0; i < PER; ++i) {
        int idx = base + i;
        if (idx < n) { rowptr[idx] = run; run += cnt[idx]; }
        else if (idx == n) rowptr[idx] = run;
    }
}

__global__ void scatter_kernel(const int* __restrict__ src, const int* __restrict__ dst,
                               const float* __restrict__ ew,
                               const int* __restrict__ rowptr, int* __restrict__ cursor,
                               int* __restrict__ csr_src, float* __restrict__ csr_w, int E) {
    int e = blockIdx.x * 256 + threadIdx.x;
    if (e >= E) return;
    int d = dst[e];
    int pos = atomicAdd(&cursor[d], 1);
    int idx = rowptr[d] + pos;
    csr_src[idx] = src[e];
    csr_w[idx]  = ew[e];
}

// ---------------------------------------------------------------------------
// fp32 GEMM with bias: C[M,N] = A[M,K] @ W[K,N] + bias[N]
// 64x128 tile, BK=16, 256 threads, 4 rows x 8 cols per thread.
// As stored transposed [K][M] so the A fragment is one ds_read_b128.
// Thread's 8 cols split as {tx*4..+3} and {64+tx*4..+3} -> all LDS accesses
// are <=2-way bank aliased (free on CDNA4).
// ---------------------------------------------------------------------------
#define TBM 64
#define TBN 128
#define TBK 16

__global__ __launch_bounds__(256) void gemm_bias_kernel(
    const float* __restrict__ A, const float* __restrict__ W,
    const float* __restrict__ bias, float* __restrict__ Cout,
    int M, int N, int K)
{
    __shared__ float As[TBK][TBM + 4];   // stride 68 words (16B-aligned rows)
    __shared__ float Bs[TBK][TBN + 4];   // stride 132 words (16B-aligned rows)

    int tid = threadIdx.x;
    int bm = blockIdx.x * TBM;
    int bn = blockIdx.y * TBN;
    int tx = tid & 15;          // column group (16)
    int ty = tid >> 4;          // row group (16) -> rows ty*4..ty*4+3

    int arow = tid >> 2, ak = (tid & 3) * 4;   // A staging: one float4 along K
    int brow = tid >> 4, bcol = (tid & 15) * 4; // B staging: two float4s per thread

    float acc[4][8] = {};

    for (int k0 = 0; k0 < K; k0 += TBK) {
        // ---- stage A (transposed into LDS)
        float4 av = make_float4(0.f, 0.f, 0.f, 0.f);
        if (bm + arow < M)
            av = *reinterpret_cast<const float4*>(A + (size_t)(bm + arow) * K + k0 + ak);
        As[ak + 0][arow] = av.x;
        As[ak + 1][arow] = av.y;
        As[ak + 2][arow] = av.z;
        As[ak + 3][arow] = av.w;
        // ---- stage B
        const float* wrow = W + (size_t)(k0 + brow) * N + bn;
        float4 b0 = *reinterpret_cast<const float4*>(wrow + bcol);
        float4 b1 = *reinterpret_cast<const float4*>(wrow + 64 + bcol);
        *reinterpret_cast<float4*>(&Bs[brow][bcol]) = b0;
        *reinterpret_cast<float4*>(&Bs[brow][64 + bcol]) = b1;
        __syncthreads();

        #pragma unroll
        for (int kk = 0; kk < TBK; ++kk) {
            float4 a = *reinterpret_cast<const float4*>(&As[kk][ty * 4]);
            float4 u = *reinterpret_cast<const float4*>(&Bs[kk][tx * 4]);
            float4 v = *reinterpret_cast<const float4*>(&Bs[kk][64 + tx * 4]);
            float ar[4] = {a.x, a.y, a.z, a.w};
            float br[8] = {u.x, u.y, u.z, u.w, v.x, v.y, v.z, v.w};
            #pragma unroll
            for (int i = 0; i < 4; ++i)
                #pragma unroll
                for (int j = 0; j < 8; ++j)
                    acc[i][j] += ar[i] * br[j];
        }
        __syncthreads();
    }

    float4 bb0 = *reinterpret_cast<const float4*>(bias + bn + tx * 4);
    float4 bb1 = *reinterpret_cast<const float4*>(bias + bn + 64 + tx * 4);
    float bbr[8] = {bb0.x, bb0.y, bb0.z, bb0.w, bb1.x, bb1.y, bb1.z, bb1.w};
    #pragma unroll
    for (int i = 0; i < 4; ++i) {
        int row = bm + ty * 4 + i;
        if (row < M) {
            float4 o0, o1;
            o0.x = acc[i][0] + bbr[0]; o0.y = acc[i][1] + bbr[1];
            o0.z = acc[i][2] + bbr[2]; o0.w = acc[i][3] + bbr[3];
            o1.x = acc[i][4] + bbr[4]; o1.y = acc[i][5] + bbr[5];
            o1.z = acc[i][6] + bbr[6]; o1.w = acc[i][7] + bbr[7];
            float* crow = Cout + (size_t)row * N + bn;
            *reinterpret_cast<float4*>(crow + tx * 4) = o0;
            *reinterpret_cast<float4*>(crow + 64 + tx * 4) = o1;
        }
    }
}

// ---------------------------------------------------------------------------
// Fused edge attention: online softmax (flash-style), single pass over the
// incoming edges of each (node, head). One wave per (node, head). No logits
// workspace; xl[src] gathered exactly once per edge.
// ---------------------------------------------------------------------------
template<int C, int H, bool DO_ELU>
__global__ __launch_bounds__(256) void edge_attn_kernel(
    const float* __restrict__ xl, const float* __restrict__ xr,
    const int* __restrict__ rowptr, const int* __restrict__ csr_src,
    const float* __restrict__ csr_w,
    const float* __restrict__ We, const float* __restrict__ att,
    const float* __restrict__ bias,
    float* __restrict__ out, int nt)
{
    constexpr int VPT = C / 64;
    int gwave = (blockIdx.x * 256 + threadIdx.x) >> 6;
    int lane = threadIdx.x & 63;
    if (gwave >= nt * H) return;
    int node = gwave / H;
    int h = gwave - node * H;
    int c0 = lane * VPT;

    size_t nbase = ((size_t)node * H + h) * C + c0;

    float xr_reg[VPT], we_reg[VPT], att_reg[VPT], bias_reg[VPT];
    #pragma unroll
    for (int v = 0; v < VPT; ++v) {
        xr_reg[v]   = xr[nbase + v];
        we_reg[v]   = We[h * C + c0 + v];
        att_reg[v]  = att[h * C + c0 + v];
        bias_reg[v] = bias[h * C + c0 + v];
    }

    int rs = rowptr[node];
    int re = rowptr[node + 1];

    float m = -INFINITY;
    float ssum = 0.f;
    float av[VPT];
    #pragma unroll
    for (int v = 0; v < VPT; ++v) av[v] = 0.f;

    for (int i = rs; i < re; ++i) {
        int s = csr_src[i];
        float w = csr_w[i];
        const float* xlp = xl + ((size_t)s * H + h) * C + c0;
        float xlv[VPT];
        if (VPT == 2) {
            float2 t = *reinterpret_cast<const float2*>(xlp);
            xlv[0] = t.x; xlv[1] = t.y;
        } else {
            float4 t = *reinterpret_cast<const float4*>(xlp);
            xlv[0] = t.x; xlv[1] = t.y; xlv[2] = t.z; xlv[3] = t.w;
        }
        // logit = att . leaky_relu(xl + xr + w*We)
        float acc = 0.f;
        #pragma unroll
        for (int v = 0; v < VPT; ++v) {
            float t = xlv[v] + xr_reg[v] + w * we_reg[v];
            t = (t > 0.f) ? t : 0.2f * t;
            acc += t * att_reg[v];
        }
        #pragma unroll
        for (int off = 32; off > 0; off >>= 1) acc += __shfl_xor(acc, off, 64);

        // online softmax update
        float newm = fmaxf(m, acc);
        float fac = __expf(m - newm);     // 0 on first edge (m=-inf)
        float p = __expf(acc - newm);
        ssum = ssum * fac + p;
        #pragma unroll
        for (int v = 0; v < VPT; ++v) av[v] = av[v] * fac + p * xlv[v];
        m = newm;
    }

    float inv = 1.f / (ssum + 1e-16f);
    #pragma unroll
    for (int v = 0; v < VPT; ++v) {
        float o = av[v] * inv + bias_reg[v];
        if (DO_ELU) o = (o > 0.f) ? o : (__expf(o) - 1.f);
        out[nbase + v] = o;
    }
}

// ---------------------------------------------------------------------------
extern "C" void kernel_launch(void* const* d_in, const int* in_sizes, int n_in,
                              void* d_out, int out_size, void* d_ws, size_t ws_size,
                              hipStream_t stream) {
    const float* x   = (const float*)d_in[0];
    const int*   ei  = (const int*)d_in[1];
    const float* ew  = (const float*)d_in[2];
    const int* srcp = ei;
    const int* dstp = ei + NE;

    const float* Wl[3]; const float* bl[3]; const float* Wr[3]; const float* br[3];
    const float* We[3]; const float* at[3]; const float* bi[3];
    for (int l = 0; l < 3; ++l) {
        int b = 3 + 7 * l;
        Wl[l] = (const float*)d_in[b + 0];
        bl[l] = (const float*)d_in[b + 1];
        Wr[l] = (const float*)d_in[b + 2];
        br[l] = (const float*)d_in[b + 3];
        We[l] = (const float*)d_in[b + 4];
        at[l] = (const float*)d_in[b + 5];
        bi[l] = (const float*)d_in[b + 6];
    }

    size_t off = 0;
    auto alloc = [&](size_t bytes) -> void* {
        void* p = (char*)d_ws + off;
        off += (bytes + 255) & ~(size_t)255;
        return p;
    };
    float* xl      = (float*)alloc((size_t)NT * 512 * 4);
    float* xr      = (float*)alloc((size_t)NT * 512 * 4);
    float* act     = (float*)alloc((size_t)NT * 512 * 4);
    int*   rowptr  = (int*)alloc((size_t)(NT + 1) * 4);
    int*   cnt     = (int*)alloc((size_t)NT * 4);
    int*   cursor  = (int*)alloc((size_t)NT * 4);
    int*   csr_src = (int*)alloc((size_t)NE * 4);
    float* csr_w   = (float*)alloc((size_t)NE * 4);

    hipMemsetAsync(cnt, 0, (size_t)NT * 4, stream);
    hipMemsetAsync(cursor, 0, (size_t)NT * 4, stream);

    int eblocks = (NE + 255) / 256;
    hist_kernel<<<eblocks, 256, 0, stream>>>(dstp, cnt, NE);
    scan_kernel<<<1, 1024, 0, stream>>>(cnt, rowptr, NT);
    scatter_kernel<<<eblocks, 256, 0, stream>>>(srcp, dstp, ew, rowptr, cursor,
                                                csr_src, csr_w, NE);

    int mblocks = (NT + TBM - 1) / TBM;

    // ---- Layer 0: K=64, N=512, H=4, C=128, ELU
    {
        dim3 g(mblocks, 512 / TBN);
        gemm_bias_kernel<<<g, 256, 0, stream>>>(x, Wl[0], bl[0], xl, NT, 512, 64);
        gemm_bias_kernel<<<g, 256, 0, stream>>>(x, Wr[0], br[0], xr, NT, 512, 64);
        int blocks = (NT * HEADS + 3) / 4;
        edge_attn_kernel<128, 4, true><<<blocks, 256, 0, stream>>>(
            xl, xr, rowptr, csr_src, csr_w, We[0], at[0], bi[0], act, NT);
    }

    // ---- Layer 1: K=512, N=512, H=4, C=128, ELU
    {
        dim3 g(mblocks, 512 / TBN);
        gemm_bias_kernel<<<g, 256, 0, stream>>>(act, Wl[1], bl[1], xl, NT, 512, 512);
        gemm_bias_kernel<<<g, 256, 0, stream>>>(act, Wr[1], br[1], xr, NT, 512, 512);
        int blocks = (NT * HEADS + 3) / 4;
        edge_attn_kernel<128, 4, true><<<blocks, 256, 0, stream>>>(
            xl, xr, rowptr, csr_src, csr_w, We[1], at[1], bi[1], act, NT);
    }

    // ---- Layer 2: K=512, N=256, H=1, C=256, no ELU, write d_out
    {
        dim3 g(mblocks, 256 / TBN);
        gemm_bias_kernel<<<g, 256, 0, stream>>>(act, Wl[2], bl[2], xl, NT, 256, 512);
        gemm_bias_kernel<<<g, 256, 0, stream>>>(act, Wr[2], br[2], xr, NT, 256, 512);
        int blocks = (NT + 3) / 4;
        edge_attn_kernel<256, 1, false><<<blocks, 256, 0, stream>>>(
            xl, xr, rowptr, csr_src, csr_w, We[2], at[2], bi[2], (float*)d_out, NT);
    }
}

// Round 3
// 419.083 us; speedup vs baseline: 1.7145x; 1.4108x over previous
//
#include <hip/hip_runtime.h>
#include <hip/hip_bf16.h>
#include <math.h>

// Problem constants (fixed by the reference)
#define NT    10000      // total nodes (BL*N)
#define NE    120000     // edges
#define HEADS 4
#define MP    10112      // NT padded to 79*128 (GEMM row tiles)

using h8    = __attribute__((ext_vector_type(8))) _Float16;
using f32x4 = __attribute__((ext_vector_type(4))) float;

// ---------------------------------------------------------------------------
// CSR build: histogram by dst -> exclusive scan -> scatter (src, weight)
// ---------------------------------------------------------------------------
__global__ void hist_kernel(const int* __restrict__ dst, int* __restrict__ cnt, int E) {
    int e = blockIdx.x * 256 + threadIdx.x;
    if (e < E) atomicAdd(&cnt[dst[e]], 1);
}

__global__ __launch_bounds__(1024) void scan_kernel(const int* __restrict__ cnt,
                                                    int* __restrict__ rowptr, int n) {
    __shared__ int part[1024];
    int tid = threadIdx.x;
    const int PER = (n + 1023) / 1024 + 1;
    int base = tid * PER;
    int s = 0;
    for (int i = 0; i < PER; ++i) {
        int idx = base + i;
        if (idx < n) s += cnt[idx];
    }
    part[tid] = s;
    __syncthreads();
    for (int off = 1; off < 1024; off <<= 1) {
        int v = (tid >= off) ? part[tid - off] : 0;
        __syncthreads();
        part[tid] += v;
        __syncthreads();
    }
    int run = (tid == 0) ? 0 : part[tid - 1];
    for (int i = 0; i < PER; ++i) {
        int idx = base + i;
        if (idx < n) { rowptr[idx] = run; run += cnt[idx]; }
        else if (idx == n) rowptr[idx] = run;
    }
}

__global__ void scatter_kernel(const int* __restrict__ src, const int* __restrict__ dst,
                               const float* __restrict__ ew,
                               const int* __restrict__ rowptr, int* __restrict__ cursor,
                               int* __restrict__ csr_src, float* __restrict__ csr_w, int E) {
    int e = blockIdx.x * 256 + threadIdx.x;
    if (e >= E) return;
    int d = dst[e];
    int pos = atomicAdd(&cursor[d], 1);
    int idx = rowptr[d] + pos;
    csr_src[idx] = src[e];
    csr_w[idx]  = ew[e];
}

// ---------------------------------------------------------------------------
// fp32 -> (hi,lo) fp16 split, elementwise (for the input x)
// ---------------------------------------------------------------------------
__global__ void split_kernel(const float* __restrict__ X, _Float16* __restrict__ hi,
                             _Float16* __restrict__ lo, int n) {
    int i = blockIdx.x * 256 + threadIdx.x;
    if (i < n) {
        float v = X[i];
        _Float16 h = (_Float16)v;
        hi[i] = h;
        lo[i] = (_Float16)(v - (float)h);
    }
}

// ---------------------------------------------------------------------------
// Weight transpose + split: W[K][N] fp32 -> WT_hi[N][K], WT_lo[N][K] fp16
// ---------------------------------------------------------------------------
__global__ void wsplit_kernel(const float* __restrict__ W, _Float16* __restrict__ Thi,
                              _Float16* __restrict__ Tlo, int K, int N) {
    __shared__ float t[32][33];
    int bk = blockIdx.x * 32, bn = blockIdx.y * 32;
    int tx = threadIdx.x, ty = threadIdx.y;   // (32, 8)
    #pragma unroll
    for (int i = 0; i < 4; ++i)
        t[ty * 4 + i][tx] = W[(size_t)(bk + ty * 4 + i) * N + bn + tx];
    __syncthreads();
    #pragma unroll
    for (int i = 0; i < 4; ++i) {
        int nn = ty * 4 + i;
        float v = t[tx][nn];
        _Float16 h = (_Float16)v;
        Thi[(size_t)(bn + nn) * K + bk + tx] = h;
        Tlo[(size_t)(bn + nn) * K + bk + tx] = (_Float16)(v - (float)h);
    }
}

// ---------------------------------------------------------------------------
// Split-fp16 MFMA GEMM, Wl & Wr fused: computes xl = A@Wl + bl and
// xr = A@Wr + br in one dispatch. A given as (hi,lo) fp16 [M][K];
// weights pre-transposed+split WT[N][K] fp16.
// 128x128 tile, BK=32, 4 waves; wave w stages one LDS buffer via
// global_load_lds (width 16); XOR swizzle slot = q ^ (row&3) makes the
// ds_read_b128 fragment loads bank-balanced without padding.
// D = Ah*Bh + Ah*Bl + Al*Bh (3 MFMA terms ~ 22-bit mantissa).
// ---------------------------------------------------------------------------
#define BM 128
#define BK 32

__global__ __launch_bounds__(256, 2) void gemm_mfma_kernel(
    const _Float16* __restrict__ Ahi, const _Float16* __restrict__ Alo,
    const _Float16* __restrict__ WlThi, const _Float16* __restrict__ WlTlo,
    const _Float16* __restrict__ WrThi, const _Float16* __restrict__ WrTlo,
    const float* __restrict__ biasl, const float* __restrict__ biasr,
    float* __restrict__ outl, float* __restrict__ outr,
    int M, int N, int K)
{
    __shared__ _Float16 sAhi[BM * BK];
    __shared__ _Float16 sAlo[BM * BK];
    __shared__ _Float16 sBhi[BM * BK];
    __shared__ _Float16 sBlo[BM * BK];

    int tid = threadIdx.x;
    int wave = tid >> 6, lane = tid & 63;
    int bm = blockIdx.x * BM;
    int nby = N >> 7;                    // 128-col blocks per side
    int by = blockIdx.y;
    bool isR = by >= nby;
    int bnn = (isR ? by - nby : by) << 7;
    const _Float16* Bh = isR ? WrThi : WlThi;
    const _Float16* Bl = isR ? WrTlo : WlTlo;
    const float* bias  = isR ? biasr : biasl;
    float* out         = isR ? outr : outl;

    // staging assignment: wave w owns one LDS buffer
    _Float16* sbuf = (wave == 0) ? sAhi : (wave == 1) ? sAlo : (wave == 2) ? sBhi : sBlo;
    const _Float16* gsrc = (wave == 0) ? Ahi : (wave == 1) ? Alo : (wave == 2) ? Bh : Bl;
    int rowbase = (wave < 2) ? bm : bnn;

    int lr = lane >> 2;        // row within a 16-row staging chunk
    int ls = lane & 3;         // 16B slot within row
    int fq = lane >> 4;        // fragment quad
    int fc = lane & 15;        // fragment row/col within tile
    int wm = (wave & 1) << 6;  // wave sub-tile origin
    int wn = (wave >> 1) << 6;
    int fslot = (fq ^ (fc & 3)) << 3;   // swizzled k-slot (halves)

    f32x4 acc[4][4] = {};

    for (int k0 = 0; k0 < K; k0 += BK) {
        __syncthreads();   // previous iteration's fragment reads complete
        #pragma unroll
        for (int t = 0; t < 8; ++t) {
            int r = t * 16 + lr;
            int g = ls ^ (r & 3);
            const _Float16* gp = gsrc + (size_t)(rowbase + r) * K + k0 + g * 8;
            __builtin_amdgcn_global_load_lds(
                (const __attribute__((address_space(1))) void*)gp,
                (__attribute__((address_space(3))) void*)(sbuf + t * 512),
                16, 0, 0);
        }
        __syncthreads();   // staging visible (drains vmcnt)

        h8 ah[4], al[4], bh[4], bl[4];
        #pragma unroll
        for (int i = 0; i < 4; ++i) {
            int m = wm + i * 16 + fc;
            int off = m * 32 + fslot;
            ah[i] = *(const h8*)(sAhi + off);
            al[i] = *(const h8*)(sAlo + off);
            int n = wn + i * 16 + fc;
            int offb = n * 32 + fslot;
            bh[i] = *(const h8*)(sBhi + offb);
            bl[i] = *(const h8*)(sBlo + offb);
        }
        #pragma unroll
        for (int i = 0; i < 4; ++i)
            #pragma unroll
            for (int j = 0; j < 4; ++j) {
                acc[i][j] = __builtin_amdgcn_mfma_f32_16x16x32_f16(ah[i], bh[j], acc[i][j], 0, 0, 0);
                acc[i][j] = __builtin_amdgcn_mfma_f32_16x16x32_f16(ah[i], bl[j], acc[i][j], 0, 0, 0);
                acc[i][j] = __builtin_amdgcn_mfma_f32_16x16x32_f16(al[i], bh[j], acc[i][j], 0, 0, 0);
            }
    }

    // epilogue: C/D layout col=lane&15, row=(lane>>4)*4+reg
    #pragma unroll
    for (int j = 0; j < 4; ++j) {
        int col = bnn + wn + j * 16 + fc;
        float bv = bias[col];
        #pragma unroll
        for (int i = 0; i < 4; ++i) {
            int row0 = bm + wm + i * 16 + fq * 4;
            #pragma unroll
            for (int reg = 0; reg < 4; ++reg) {
                int row = row0 + reg;
                if (row < M)
                    out[(size_t)row * N + col] = acc[i][j][reg] + bv;
            }
        }
    }
}

// ---------------------------------------------------------------------------
// Fused edge attention (online softmax, single pass). One wave per
// (node, head). SPLIT: emit (hi,lo) fp16 for the next layer's GEMM A.
// ---------------------------------------------------------------------------
template<int C, int H, bool DO_ELU, bool SPLIT>
__global__ __launch_bounds__(256) void edge_attn_kernel(
    const float* __restrict__ xl, const float* __restrict__ xr,
    const int* __restrict__ rowptr, const int* __restrict__ csr_src,
    const float* __restrict__ csr_w,
    const float* __restrict__ We, const float* __restrict__ att,
    const float* __restrict__ bias,
    float* __restrict__ out, _Float16* __restrict__ out_hi,
    _Float16* __restrict__ out_lo, int nt)
{
    constexpr int VPT = C / 64;
    int gwave = (blockIdx.x * 256 + threadIdx.x) >> 6;
    int lane = threadIdx.x & 63;
    if (gwave >= nt * H) return;
    int node = gwave / H;
    int h = gwave - node * H;
    int c0 = lane * VPT;

    size_t nbase = ((size_t)node * H + h) * C + c0;

    float xr_reg[VPT], we_reg[VPT], att_reg[VPT], bias_reg[VPT];
    #pragma unroll
    for (int v = 0; v < VPT; ++v) {
        xr_reg[v]   = xr[nbase + v];
        we_reg[v]   = We[h * C + c0 + v];
        att_reg[v]  = att[h * C + c0 + v];
        bias_reg[v] = bias[h * C + c0 + v];
    }

    int rs = rowptr[node];
    int re = rowptr[node + 1];

    float m = -INFINITY;
    float ssum = 0.f;
    float av[VPT];
    #pragma unroll
    for (int v = 0; v < VPT; ++v) av[v] = 0.f;

    for (int i = rs; i < re; ++i) {
        int s = csr_src[i];
        float w = csr_w[i];
        const float* xlp = xl + ((size_t)s * H + h) * C + c0;
        float xlv[VPT];
        if (VPT == 2) {
            float2 t = *reinterpret_cast<const float2*>(xlp);
            xlv[0] = t.x; xlv[1] = t.y;
        } else {
            float4 t = *reinterpret_cast<const float4*>(xlp);
            xlv[0] = t.x; xlv[1] = t.y; xlv[2] = t.z; xlv[3] = t.w;
        }
        float acc = 0.f;
        #pragma unroll
        for (int v = 0; v < VPT; ++v) {
            float t = xlv[v] + xr_reg[v] + w * we_reg[v];
            t = (t > 0.f) ? t : 0.2f * t;
            acc += t * att_reg[v];
        }
        #pragma unroll
        for (int off = 32; off > 0; off >>= 1) acc += __shfl_xor(acc, off, 64);

        float newm = fmaxf(m, acc);
        float fac = __expf(m - newm);
        float p = __expf(acc - newm);
        ssum = ssum * fac + p;
        #pragma unroll
        for (int v = 0; v < VPT; ++v) av[v] = av[v] * fac + p * xlv[v];
        m = newm;
    }

    float inv = 1.f / (ssum + 1e-16f);
    #pragma unroll
    for (int v = 0; v < VPT; ++v) {
        float o = av[v] * inv + bias_reg[v];
        if (DO_ELU) o = (o > 0.f) ? o : (__expf(o) - 1.f);
        if (SPLIT) {
            _Float16 hh = (_Float16)o;
            out_hi[nbase + v] = hh;
            out_lo[nbase + v] = (_Float16)(o - (float)hh);
        } else {
            out[nbase + v] = o;
        }
    }
}

// ---------------------------------------------------------------------------
extern "C" void kernel_launch(void* const* d_in, const int* in_sizes, int n_in,
                              void* d_out, int out_size, void* d_ws, size_t ws_size,
                              hipStream_t stream) {
    const float* x   = (const float*)d_in[0];
    const int*   ei  = (const int*)d_in[1];
    const float* ew  = (const float*)d_in[2];
    const int* srcp = ei;
    const int* dstp = ei + NE;

    const float* Wl[3]; const float* bl[3]; const float* Wr[3]; const float* br[3];
    const float* We[3]; const float* at[3]; const float* bi[3];
    for (int l = 0; l < 3; ++l) {
        int b = 3 + 7 * l;
        Wl[l] = (const float*)d_in[b + 0];
        bl[l] = (const float*)d_in[b + 1];
        Wr[l] = (const float*)d_in[b + 2];
        br[l] = (const float*)d_in[b + 3];
        We[l] = (const float*)d_in[b + 4];
        at[l] = (const float*)d_in[b + 5];
        bi[l] = (const float*)d_in[b + 6];
    }

    size_t off = 0;
    auto alloc = [&](size_t bytes) -> void* {
        void* p = (char*)d_ws + off;
        off += (bytes + 255) & ~(size_t)255;
        return p;
    };
    float*    xl      = (float*)alloc((size_t)MP * 512 * 4);
    float*    xr      = (float*)alloc((size_t)MP * 512 * 4);
    _Float16* acthi   = (_Float16*)alloc((size_t)MP * 512 * 2);
    _Float16* actlo   = (_Float16*)alloc((size_t)MP * 512 * 2);
    _Float16* xhi     = (_Float16*)alloc((size_t)MP * 64 * 2);
    _Float16* xlo     = (_Float16*)alloc((size_t)MP * 64 * 2);
    // transposed+split weights: [N][K] fp16 each
    _Float16* wt[3][4]; // [layer][{l_hi,l_lo,r_hi,r_lo}]
    const int KD[3] = {64, 512, 512};
    const int ND[3] = {512, 512, 256};
    for (int l = 0; l < 3; ++l)
        for (int q = 0; q < 4; ++q)
            wt[l][q] = (_Float16*)alloc((size_t)KD[l] * ND[l] * 2);
    int*   rowptr  = (int*)alloc((size_t)(NT + 1) * 4);
    int*   cnt     = (int*)alloc((size_t)NT * 4);
    int*   cursor  = (int*)alloc((size_t)NT * 4);
    int*   csr_src = (int*)alloc((size_t)NE * 4);
    float* csr_w   = (float*)alloc((size_t)NE * 4);

    hipMemsetAsync(cnt, 0, (size_t)NT * 4, stream);
    hipMemsetAsync(cursor, 0, (size_t)NT * 4, stream);

    int eblocks = (NE + 255) / 256;
    hist_kernel<<<eblocks, 256, 0, stream>>>(dstp, cnt, NE);
    scan_kernel<<<1, 1024, 0, stream>>>(cnt, rowptr, NT);
    scatter_kernel<<<eblocks, 256, 0, stream>>>(srcp, dstp, ew, rowptr, cursor,
                                                csr_src, csr_w, NE);

    // input split + weight transpose/split
    split_kernel<<<(NT * 64 + 255) / 256, 256, 0, stream>>>(x, xhi, xlo, NT * 64);
    for (int l = 0; l < 3; ++l) {
        dim3 g(KD[l] / 32, ND[l] / 32), b(32, 8);
        wsplit_kernel<<<g, b, 0, stream>>>(Wl[l], wt[l][0], wt[l][1], KD[l], ND[l]);
        wsplit_kernel<<<g, b, 0, stream>>>(Wr[l], wt[l][2], wt[l][3], KD[l], ND[l]);
    }

    int mblocks = (NT + BM - 1) / BM;   // 79

    // ---- Layer 0: K=64, N=512/side, H=4, C=128, ELU
    {
        dim3 g(mblocks, 2 * (512 / 128));
        gemm_mfma_kernel<<<g, 256, 0, stream>>>(
            xhi, xlo, wt[0][0], wt[0][1], wt[0][2], wt[0][3],
            bl[0], br[0], xl, xr, NT, 512, 64);
        int blocks = (NT * HEADS + 3) / 4;
        edge_attn_kernel<128, 4, true, true><<<blocks, 256, 0, stream>>>(
            xl, xr, rowptr, csr_src, csr_w, We[0], at[0], bi[0],
            nullptr, acthi, actlo, NT);
    }

    // ---- Layer 1: K=512, N=512/side
    {
        dim3 g(mblocks, 2 * (512 / 128));
        gemm_mfma_kernel<<<g, 256, 0, stream>>>(
            acthi, actlo, wt[1][0], wt[1][1], wt[1][2], wt[1][3],
            bl[1], br[1], xl, xr, NT, 512, 512);
        int blocks = (NT * HEADS + 3) / 4;
        edge_attn_kernel<128, 4, true, true><<<blocks, 256, 0, stream>>>(
            xl, xr, rowptr, csr_src, csr_w, We[1], at[1], bi[1],
            nullptr, acthi, actlo, NT);
    }

    // ---- Layer 2: K=512, N=256/side, H=1, C=256, no ELU -> d_out
    {
        dim3 g(mblocks, 2 * (256 / 128));
        gemm_mfma_kernel<<<g, 256, 0, stream>>>(
            acthi, actlo, wt[2][0], wt[2][1], wt[2][2], wt[2][3],
            bl[2], br[2], xl, xr, NT, 256, 512);
        int blocks = (NT + 3) / 4;
        edge_attn_kernel<256, 1, false, false><<<blocks, 256, 0, stream>>>(
            xl, xr, rowptr, csr_src, csr_w, We[2], at[2], bi[2],
            (float*)d_out, nullptr, nullptr, NT);
    }
}

// Round 4
// 368.448 us; speedup vs baseline: 1.9501x; 1.1374x over previous
//
#include <hip/hip_runtime.h>
#include <hip/hip_bf16.h>
#include <math.h>

// Problem constants (fixed by the reference)
#define NT    10000      // total nodes (BL*N)
#define NE    120000     // edges
#define HEADS 4
#define MP    10112      // NT padded to 79*128 (GEMM row tiles)

using h8    = __attribute__((ext_vector_type(8))) _Float16;
using f32x4 = __attribute__((ext_vector_type(4))) float;

// ---------------------------------------------------------------------------
// CSR build: histogram by dst -> exclusive scan -> scatter (src, weight)
// ---------------------------------------------------------------------------
__global__ void hist_kernel(const int* __restrict__ dst, int* __restrict__ cnt, int E) {
    int e = blockIdx.x * 256 + threadIdx.x;
    if (e < E) atomicAdd(&cnt[dst[e]], 1);
}

__global__ __launch_bounds__(1024) void scan_kernel(const int* __restrict__ cnt,
                                                    int* __restrict__ rowptr, int n) {
    __shared__ int part[1024];
    int tid = threadIdx.x;
    const int PER = (n + 1023) / 1024 + 1;
    int base = tid * PER;
    int s = 0;
    for (int i = 0; i < PER; ++i) {
        int idx = base + i;
        if (idx < n) s += cnt[idx];
    }
    part[tid] = s;
    __syncthreads();
    for (int off = 1; off < 1024; off <<= 1) {
        int v = (tid >= off) ? part[tid - off] : 0;
        __syncthreads();
        part[tid] += v;
        __syncthreads();
    }
    int run = (tid == 0) ? 0 : part[tid - 1];
    for (int i = 0; i < PER; ++i) {
        int idx = base + i;
        if (idx < n) { rowptr[idx] = run; run += cnt[idx]; }
        else if (idx == n) rowptr[idx] = run;
    }
}

__global__ void scatter_kernel(const int* __restrict__ src, const int* __restrict__ dst,
                               const float* __restrict__ ew,
                               const int* __restrict__ rowptr, int* __restrict__ cursor,
                               int* __restrict__ csr_src, float* __restrict__ csr_w, int E) {
    int e = blockIdx.x * 256 + threadIdx.x;
    if (e >= E) return;
    int d = dst[e];
    int pos = atomicAdd(&cursor[d], 1);
    int idx = rowptr[d] + pos;
    csr_src[idx] = src[e];
    csr_w[idx]  = ew[e];
}

// ---------------------------------------------------------------------------
// fp32 -> (hi,lo) fp16 split, elementwise (for the input x)
// ---------------------------------------------------------------------------
__global__ void split_kernel(const float* __restrict__ X, _Float16* __restrict__ hi,
                             _Float16* __restrict__ lo, int n) {
    int i = blockIdx.x * 256 + threadIdx.x;
    if (i < n) {
        float v = X[i];
        _Float16 h = (_Float16)v;
        hi[i] = h;
        lo[i] = (_Float16)(v - (float)h);
    }
}

// ---------------------------------------------------------------------------
// Weight transpose + split: W[K][N] fp32 -> WT_hi[N][K], WT_lo[N][K] fp16
// ---------------------------------------------------------------------------
__global__ void wsplit_kernel(const float* __restrict__ W, _Float16* __restrict__ Thi,
                              _Float16* __restrict__ Tlo, int K, int N) {
    __shared__ float t[32][33];
    int bk = blockIdx.x * 32, bn = blockIdx.y * 32;
    int tx = threadIdx.x, ty = threadIdx.y;   // (32, 8)
    #pragma unroll
    for (int i = 0; i < 4; ++i)
        t[ty * 4 + i][tx] = W[(size_t)(bk + ty * 4 + i) * N + bn + tx];
    __syncthreads();
    #pragma unroll
    for (int i = 0; i < 4; ++i) {
        int nn = ty * 4 + i;
        float v = t[tx][nn];
        _Float16 h = (_Float16)v;
        Thi[(size_t)(bn + nn) * K + bk + tx] = h;
        Tlo[(size_t)(bn + nn) * K + bk + tx] = (_Float16)(v - (float)h);
    }
}

// ---------------------------------------------------------------------------
// Split-fp16 MFMA GEMM, Wl & Wr fused (unchanged from round 3).
// ---------------------------------------------------------------------------
#define BM 128
#define BK 32

__global__ __launch_bounds__(256, 2) void gemm_mfma_kernel(
    const _Float16* __restrict__ Ahi, const _Float16* __restrict__ Alo,
    const _Float16* __restrict__ WlThi, const _Float16* __restrict__ WlTlo,
    const _Float16* __restrict__ WrThi, const _Float16* __restrict__ WrTlo,
    const float* __restrict__ biasl, const float* __restrict__ biasr,
    float* __restrict__ outl, float* __restrict__ outr,
    int M, int N, int K)
{
    __shared__ _Float16 sAhi[BM * BK];
    __shared__ _Float16 sAlo[BM * BK];
    __shared__ _Float16 sBhi[BM * BK];
    __shared__ _Float16 sBlo[BM * BK];

    int tid = threadIdx.x;
    int wave = tid >> 6, lane = tid & 63;
    int bm = blockIdx.x * BM;
    int nby = N >> 7;
    int by = blockIdx.y;
    bool isR = by >= nby;
    int bnn = (isR ? by - nby : by) << 7;
    const _Float16* Bh = isR ? WrThi : WlThi;
    const _Float16* Bl = isR ? WrTlo : WlTlo;
    const float* bias  = isR ? biasr : biasl;
    float* out         = isR ? outr : outl;

    _Float16* sbuf = (wave == 0) ? sAhi : (wave == 1) ? sAlo : (wave == 2) ? sBhi : sBlo;
    const _Float16* gsrc = (wave == 0) ? Ahi : (wave == 1) ? Alo : (wave == 2) ? Bh : Bl;
    int rowbase = (wave < 2) ? bm : bnn;

    int lr = lane >> 2;
    int ls = lane & 3;
    int fq = lane >> 4;
    int fc = lane & 15;
    int wm = (wave & 1) << 6;
    int wn = (wave >> 1) << 6;
    int fslot = (fq ^ (fc & 3)) << 3;

    f32x4 acc[4][4] = {};

    for (int k0 = 0; k0 < K; k0 += BK) {
        __syncthreads();
        #pragma unroll
        for (int t = 0; t < 8; ++t) {
            int r = t * 16 + lr;
            int g = ls ^ (r & 3);
            const _Float16* gp = gsrc + (size_t)(rowbase + r) * K + k0 + g * 8;
            __builtin_amdgcn_global_load_lds(
                (const __attribute__((address_space(1))) void*)gp,
                (__attribute__((address_space(3))) void*)(sbuf + t * 512),
                16, 0, 0);
        }
        __syncthreads();

        h8 ah[4], al[4], bh[4], bl[4];
        #pragma unroll
        for (int i = 0; i < 4; ++i) {
            int m = wm + i * 16 + fc;
            int off = m * 32 + fslot;
            ah[i] = *(const h8*)(sAhi + off);
            al[i] = *(const h8*)(sAlo + off);
            int n = wn + i * 16 + fc;
            int offb = n * 32 + fslot;
            bh[i] = *(const h8*)(sBhi + offb);
            bl[i] = *(const h8*)(sBlo + offb);
        }
        #pragma unroll
        for (int i = 0; i < 4; ++i)
            #pragma unroll
            for (int j = 0; j < 4; ++j) {
                acc[i][j] = __builtin_amdgcn_mfma_f32_16x16x32_f16(ah[i], bh[j], acc[i][j], 0, 0, 0);
                acc[i][j] = __builtin_amdgcn_mfma_f32_16x16x32_f16(ah[i], bl[j], acc[i][j], 0, 0, 0);
                acc[i][j] = __builtin_amdgcn_mfma_f32_16x16x32_f16(al[i], bh[j], acc[i][j], 0, 0, 0);
            }
    }

    #pragma unroll
    for (int j = 0; j < 4; ++j) {
        int col = bnn + wn + j * 16 + fc;
        float bv = bias[col];
        #pragma unroll
        for (int i = 0; i < 4; ++i) {
            int row0 = bm + wm + i * 16 + fq * 4;
            #pragma unroll
            for (int reg = 0; reg < 4; ++reg) {
                int row = row0 + reg;
                if (row < M)
                    out[(size_t)row * N + col] = acc[i][j][reg] + bv;
            }
        }
    }
}

// ---------------------------------------------------------------------------
// Fused edge attention, ALL HEADS merged into one wave per node.
// Lane l owns channels [l*VPT, l*VPT+VPT) of the flat H*C row; head = lane/G
// where G = 64/H. Logit reduction is a log2(G)-step shuffle within the head
// group (xor offsets < G stay in-group). Online softmax state replicated
// per lane within its group. Each edge row (H*C floats) gathered once.
// ---------------------------------------------------------------------------
template<int C, int H, bool DO_ELU, bool SPLIT>
__global__ __launch_bounds__(256) void edge_attn_kernel(
    const float* __restrict__ xl, const float* __restrict__ xr,
    const int* __restrict__ rowptr, const int* __restrict__ csr_src,
    const float* __restrict__ csr_w,
    const float* __restrict__ We, const float* __restrict__ att,
    const float* __restrict__ bias,
    float* __restrict__ out, _Float16* __restrict__ out_hi,
    _Float16* __restrict__ out_lo, int nt)
{
    constexpr int CHT = C * H;        // flat channels per node (512 or 256)
    constexpr int VPT = CHT / 64;     // channels per lane (8 or 4)
    constexpr int G   = 64 / H;       // lanes per head group (16 or 64)

    int node = (blockIdx.x * 256 + threadIdx.x) >> 6;
    int lane = threadIdx.x & 63;
    if (node >= nt) return;
    int c0 = lane * VPT;

    size_t nbase = (size_t)node * CHT + c0;

    float xr_reg[VPT], we_reg[VPT], att_reg[VPT], bias_reg[VPT];
    #pragma unroll
    for (int v = 0; v < VPT; v += 4) {
        *(float4*)(xr_reg + v)   = *(const float4*)(xr + nbase + v);
        *(float4*)(we_reg + v)   = *(const float4*)(We + c0 + v);
        *(float4*)(att_reg + v)  = *(const float4*)(att + c0 + v);
        *(float4*)(bias_reg + v) = *(const float4*)(bias + c0 + v);
    }

    int rs = rowptr[node];
    int re = rowptr[node + 1];

    float m = -INFINITY;
    float ssum = 0.f;
    float av[VPT];
    #pragma unroll
    for (int v = 0; v < VPT; ++v) av[v] = 0.f;

    for (int i = rs; i < re; ++i) {
        int s = csr_src[i];
        float w = csr_w[i];
        const float* xlp = xl + (size_t)s * CHT + c0;
        float xlv[VPT];
        #pragma unroll
        for (int v = 0; v < VPT; v += 4)
            *(float4*)(xlv + v) = *(const float4*)(xlp + v);

        // per-head logit partial: att . leaky_relu(xl + xr + w*We)
        float part = 0.f;
        #pragma unroll
        for (int v = 0; v < VPT; ++v) {
            float t = xlv[v] + xr_reg[v] + w * we_reg[v];
            t = fmaxf(t, 0.f) + 0.2f * fminf(t, 0.f);
            part += t * att_reg[v];
        }
        // reduce within the head group (xor < G stays in-group)
        #pragma unroll
        for (int off = G / 2; off > 0; off >>= 1)
            part += __shfl_xor(part, off, 64);

        // online softmax update (state per head, replicated across group)
        float newm = fmaxf(m, part);
        float fac = __expf(m - newm);
        float p = __expf(part - newm);
        ssum = ssum * fac + p;
        #pragma unroll
        for (int v = 0; v < VPT; ++v) av[v] = av[v] * fac + p * xlv[v];
        m = newm;
    }

    float inv = 1.f / (ssum + 1e-16f);
    #pragma unroll
    for (int v = 0; v < VPT; ++v) {
        float o = av[v] * inv + bias_reg[v];
        if (DO_ELU) o = (o > 0.f) ? o : (__expf(o) - 1.f);
        if (SPLIT) {
            _Float16 hh = (_Float16)o;
            out_hi[nbase + v] = hh;
            out_lo[nbase + v] = (_Float16)(o - (float)hh);
        } else {
            out[nbase + v] = o;
        }
    }
}

// ---------------------------------------------------------------------------
extern "C" void kernel_launch(void* const* d_in, const int* in_sizes, int n_in,
                              void* d_out, int out_size, void* d_ws, size_t ws_size,
                              hipStream_t stream) {
    const float* x   = (const float*)d_in[0];
    const int*   ei  = (const int*)d_in[1];
    const float* ew  = (const float*)d_in[2];
    const int* srcp = ei;
    const int* dstp = ei + NE;

    const float* Wl[3]; const float* bl[3]; const float* Wr[3]; const float* br[3];
    const float* We[3]; const float* at[3]; const float* bi[3];
    for (int l = 0; l < 3; ++l) {
        int b = 3 + 7 * l;
        Wl[l] = (const float*)d_in[b + 0];
        bl[l] = (const float*)d_in[b + 1];
        Wr[l] = (const float*)d_in[b + 2];
        br[l] = (const float*)d_in[b + 3];
        We[l] = (const float*)d_in[b + 4];
        at[l] = (const float*)d_in[b + 5];
        bi[l] = (const float*)d_in[b + 6];
    }

    size_t off = 0;
    auto alloc = [&](size_t bytes) -> void* {
        void* p = (char*)d_ws + off;
        off += (bytes + 255) & ~(size_t)255;
        return p;
    };
    float*    xl      = (float*)alloc((size_t)MP * 512 * 4);
    float*    xr      = (float*)alloc((size_t)MP * 512 * 4);
    _Float16* acthi   = (_Float16*)alloc((size_t)MP * 512 * 2);
    _Float16* actlo   = (_Float16*)alloc((size_t)MP * 512 * 2);
    _Float16* xhi     = (_Float16*)alloc((size_t)MP * 64 * 2);
    _Float16* xlo     = (_Float16*)alloc((size_t)MP * 64 * 2);
    _Float16* wt[3][4];
    const int KD[3] = {64, 512, 512};
    const int ND[3] = {512, 512, 256};
    for (int l = 0; l < 3; ++l)
        for (int q = 0; q < 4; ++q)
            wt[l][q] = (_Float16*)alloc((size_t)KD[l] * ND[l] * 2);
    int*   rowptr  = (int*)alloc((size_t)(NT + 1) * 4);
    int*   cnt     = (int*)alloc((size_t)NT * 4);
    int*   cursor  = (int*)alloc((size_t)NT * 4);
    int*   csr_src = (int*)alloc((size_t)NE * 4);
    float* csr_w   = (float*)alloc((size_t)NE * 4);

    hipMemsetAsync(cnt, 0, (size_t)NT * 4, stream);
    hipMemsetAsync(cursor, 0, (size_t)NT * 4, stream);

    int eblocks = (NE + 255) / 256;
    hist_kernel<<<eblocks, 256, 0, stream>>>(dstp, cnt, NE);
    scan_kernel<<<1, 1024, 0, stream>>>(cnt, rowptr, NT);
    scatter_kernel<<<eblocks, 256, 0, stream>>>(srcp, dstp, ew, rowptr, cursor,
                                                csr_src, csr_w, NE);

    split_kernel<<<(NT * 64 + 255) / 256, 256, 0, stream>>>(x, xhi, xlo, NT * 64);
    for (int l = 0; l < 3; ++l) {
        dim3 g(KD[l] / 32, ND[l] / 32), b(32, 8);
        wsplit_kernel<<<g, b, 0, stream>>>(Wl[l], wt[l][0], wt[l][1], KD[l], ND[l]);
        wsplit_kernel<<<g, b, 0, stream>>>(Wr[l], wt[l][2], wt[l][3], KD[l], ND[l]);
    }

    int mblocks = (NT + BM - 1) / BM;   // 79
    int nblocks = (NT + 3) / 4;         // one wave per node

    // ---- Layer 0: K=64, N=512/side, H=4, C=128, ELU
    {
        dim3 g(mblocks, 2 * (512 / 128));
        gemm_mfma_kernel<<<g, 256, 0, stream>>>(
            xhi, xlo, wt[0][0], wt[0][1], wt[0][2], wt[0][3],
            bl[0], br[0], xl, xr, NT, 512, 64);
        edge_attn_kernel<128, 4, true, true><<<nblocks, 256, 0, stream>>>(
            xl, xr, rowptr, csr_src, csr_w, We[0], at[0], bi[0],
            nullptr, acthi, actlo, NT);
    }

    // ---- Layer 1: K=512, N=512/side
    {
        dim3 g(mblocks, 2 * (512 / 128));
        gemm_mfma_kernel<<<g, 256, 0, stream>>>(
            acthi, actlo, wt[1][0], wt[1][1], wt[1][2], wt[1][3],
            bl[1], br[1], xl, xr, NT, 512, 512);
        edge_attn_kernel<128, 4, true, true><<<nblocks, 256, 0, stream>>>(
            xl, xr, rowptr, csr_src, csr_w, We[1], at[1], bi[1],
            nullptr, acthi, actlo, NT);
    }

    // ---- Layer 2: K=512, N=256/side, H=1, C=256, no ELU -> d_out
    {
        dim3 g(mblocks, 2 * (256 / 128));
        gemm_mfma_kernel<<<g, 256, 0, stream>>>(
            acthi, actlo, wt[2][0], wt[2][1], wt[2][2], wt[2][3],
            bl[2], br[2], xl, xr, NT, 256, 512);
        edge_attn_kernel<256, 1, false, false><<<nblocks, 256, 0, stream>>>(
            xl, xr, rowptr, csr_src, csr_w, We[2], at[2], bi[2],
            (float*)d_out, nullptr, nullptr, NT);
    }
}